// Round 4
// baseline (173.676 us; speedup 1.0000x reference)
//
#include <hip/hip_runtime.h>

#define N_NODES 50000
#define N_EDGES 400000
#define F_INP 5
#define HD 256          // HEADS*DIM = 2*128
#define BN_EPS 1e-5f

// ---- workspace layout (float offsets) ----
#define OFF_HBN   0            // N*8  = 400000 (padded rows: 5 used + 3 pad)
#define OFF_ACC   400000       // N*16 = 800000 (per node: den0,S0[5],den1,S1[5],cnt,pad3)

// BN1 on input features -> hbn8 [N,8] (padded for aligned 32B rows)
__global__ void k_bn1(const float* __restrict__ h, const float* __restrict__ g1,
                      const float* __restrict__ be1, const float* __restrict__ rm1,
                      const float* __restrict__ rv1, float* __restrict__ hbn8) {
    int i = blockIdx.x * blockDim.x + threadIdx.x;
    if (i >= N_NODES * 8) return;
    int f = i & 7, n = i >> 3;
    float v = 0.f;
    if (f < F_INP) {
        float x = h[n * F_INP + f];
        v = (x - rm1[f]) * rsqrtf(rv1[f] + BN_EPS) * g1[f] + be1[f];
    }
    hbn8[i] = v;
}

// Persistent waves, one edge per wave-iteration.
// Half-wave head split: lanes 0-31 -> head0 channels, lanes 32-63 -> head1.
// Per-edge node rows + indices are wave-uniform -> forced scalar (s_load).
__launch_bounds__(256)
__global__ void k_edge(const float* __restrict__ hbn8, const int* __restrict__ ei,
                       const float* __restrict__ ew,
                       const float* __restrict__ Wl, const float* __restrict__ bl,
                       const float* __restrict__ Wr, const float* __restrict__ br,
                       const float* __restrict__ We, const float* __restrict__ att,
                       float* __restrict__ acc) {
    int lane = threadIdx.x & 63;
    int wave = (int)((blockIdx.x * blockDim.x + threadIdx.x) >> 6);
    int nwaves = (int)((gridDim.x * blockDim.x) >> 6);
    int half = lane >> 5;        // head index
    int i32 = lane & 31;

    float wa[4][F_INP], wb[4][F_INP], cb[4], wev[4], at[4];
#pragma unroll
    for (int q = 0; q < 4; ++q) {
        int c = half * 128 + q * 32 + i32;
        cb[q] = bl[c] + br[c];
        wev[q] = We[c];
        at[q] = att[c];
#pragma unroll
        for (int f = 0; f < F_INP; ++f) {
            wa[q][f] = Wl[f * HD + c];
            wb[q][f] = Wr[f * HD + c];
        }
    }

    for (int e = wave; e < N_EDGES; e += nwaves) {
        int eu = __builtin_amdgcn_readfirstlane(e);
        int src = ei[eu], dst = ei[N_EDGES + eu];
        float w = ew[eu];
        int sb = src * 8, db = dst * 8;
        float hs0 = hbn8[sb + 0], hs1 = hbn8[sb + 1], hs2 = hbn8[sb + 2],
              hs3 = hbn8[sb + 3], hs4 = hbn8[sb + 4];
        float hd0 = hbn8[db + 0], hd1 = hbn8[db + 1], hd2 = hbn8[db + 2],
              hd3 = hbn8[db + 3], hd4 = hbn8[db + 4];

        float accv = 0.f;
#pragma unroll
        for (int q = 0; q < 4; ++q) {
            float u = cb[q] + w * wev[q];
            u += hs0 * wa[q][0] + hs1 * wa[q][1] + hs2 * wa[q][2]
               + hs3 * wa[q][3] + hs4 * wa[q][4];
            u += hd0 * wb[q][0] + hd1 * wb[q][1] + hd2 * wb[q][2]
               + hd3 * wb[q][3] + hd4 * wb[q][4];
            accv += at[q] * fmaxf(u, 0.2f * u);   // leaky_relu slope 0.2
        }
        // 32-lane reduce within each half
#pragma unroll
        for (int m = 16; m; m >>= 1) accv += __shfl_xor(accv, m);
        float ex = __expf(accv);              // low half: ex0, high half: ex1
        float exo = __shfl_xor(ex, 32);       // the other head's ex
        if (lane < 13) {                      // low half only: ex=ex0, exo=ex1
            int k = (lane < 6) ? lane - 1 : lane - 7;
            float hsel = hs0;
            hsel = (k == 1) ? hs1 : hsel;
            hsel = (k == 2) ? hs2 : hsel;
            hsel = (k == 3) ? hs3 : hsel;
            hsel = (k == 4) ? hs4 : hsel;
            float base = (lane < 6) ? ex : exo;
            float v = base * hsel;
            v = (lane == 0)  ? ex  : v;
            v = (lane == 6)  ? exo : v;
            v = (lane == 12) ? 1.0f : v;
            atomicAdd(&acc[dst * 16 + lane], v);
        }
    }
}

// fused: reconstruct aggregated feature from 12 moments -> fc1(LDS W1) -> BN2
//        -> lrelu -> fc2 -> out
__launch_bounds__(256, 1)
__global__ void k_mlp(const float* __restrict__ acc,
                      const float* __restrict__ Wl, const float* __restrict__ bl,
                      const float* __restrict__ bias_gat,
                      const float* __restrict__ W1, const float* __restrict__ b1,
                      const float* __restrict__ g2, const float* __restrict__ be2,
                      const float* __restrict__ rm2, const float* __restrict__ rv2,
                      const float* __restrict__ W2, const float* __restrict__ b2,
                      float* __restrict__ out) {
    __shared__ float wsh[128 * 128];
    __shared__ float xsh[8][128];
    __shared__ float wlsh[5 * 256 + 256 + 128];   // Wl | bl | bias_gat
    __shared__ float accsh[8][16];
    int t = threadIdx.x;
    for (int i = t; i < 128 * 128 / 4; i += 256)
        ((float4*)wsh)[i] = ((const float4*)W1)[i];
    for (int i = t; i < 5 * 256; i += 256) wlsh[i] = Wl[i];
    wlsh[1280 + t] = bl[t];
    if (t < 128) wlsh[1536 + t] = bias_gat[t];
    __syncthreads();
    const float* WL = wlsh;
    const float* BL = wlsh + 1280;
    const float* BG = wlsh + 1536;

    int nl = t >> 5;      // local node 0..7
    int jg = t & 31;      // output group
    int j4 = jg * 4;

    const int ngroups = (N_NODES + 7) / 8;
    for (int g = blockIdx.x; g < ngroups; g += gridDim.x) {
        int n = g * 8 + nl;
        if (t < 128) {
            int node = g * 8 + (t >> 4);
            accsh[t >> 4][t & 15] = (node < N_NODES) ? acc[node * 16 + (t & 15)] : 0.f;
        }
        __syncthreads();
        bool valid = n < N_NODES;
        if (valid) {
            float den0 = accsh[nl][0], den1 = accsh[nl][6], cntv = accsh[nl][12];
            float r0 = 1.f / (den0 + 1e-16f), r1 = 1.f / (den1 + 1e-16f);
            float scale = 0.5f / fmaxf(cntv, 1.f);
            float c0 = den0 * r0 * scale, c1 = den1 * r1 * scale;
            float T0[F_INP], T1[F_INP];
#pragma unroll
            for (int f = 0; f < F_INP; ++f) {
                T0[f] = accsh[nl][1 + f] * r0 * scale;
                T1[f] = accsh[nl][7 + f] * r1 * scale;
            }
#pragma unroll
            for (int q = 0; q < 4; ++q) {
                int d = j4 + q;
                float xv = c0 * BL[d] + c1 * BL[128 + d];
#pragma unroll
                for (int f = 0; f < F_INP; ++f)
                    xv += T0[f] * WL[f * HD + d] + T1[f] * WL[f * HD + 128 + d];
                xsh[nl][d] = xv + BG[d];
            }
            float4 a4 = *(const float4*)&b1[j4];
#pragma unroll 8
            for (int k = 0; k < 128; ++k) {
                float xv = xsh[nl][k];
                float4 w = *(const float4*)&wsh[k * 128 + j4];
                a4.x += xv * w.x; a4.y += xv * w.y;
                a4.z += xv * w.z; a4.w += xv * w.w;
            }
            float4 rm = *(const float4*)&rm2[j4];
            float4 rv = *(const float4*)&rv2[j4];
            float4 gg = *(const float4*)&g2[j4];
            float4 bb = *(const float4*)&be2[j4];
            float a[4];
            a[0] = (a4.x - rm.x) * rsqrtf(rv.x + BN_EPS) * gg.x + bb.x;
            a[1] = (a4.y - rm.y) * rsqrtf(rv.y + BN_EPS) * gg.y + bb.y;
            a[2] = (a4.z - rm.z) * rsqrtf(rv.z + BN_EPS) * gg.z + bb.z;
            a[3] = (a4.w - rm.w) * rsqrtf(rv.w + BN_EPS) * gg.w + bb.w;
#pragma unroll
            for (int q = 0; q < 4; ++q) a[q] = fmaxf(a[q], 0.01f * a[q]);
            float pf[5] = {0.f, 0.f, 0.f, 0.f, 0.f};
#pragma unroll
            for (int q = 0; q < 4; ++q)
#pragma unroll
                for (int f = 0; f < 5; ++f) pf[f] += a[q] * W2[(j4 + q) * 5 + f];
#pragma unroll
            for (int m = 16; m; m >>= 1)
#pragma unroll
                for (int f = 0; f < 5; ++f) pf[f] += __shfl_xor(pf[f], m);
            if (jg == 0) {
#pragma unroll
                for (int f = 0; f < 5; ++f) out[n * 5 + f] = pf[f] + b2[f];
            }
        }
        __syncthreads();
    }
}

extern "C" void kernel_launch(void* const* d_in, const int* in_sizes, int n_in,
                              void* d_out, int out_size, void* d_ws, size_t ws_size,
                              hipStream_t stream) {
    const float* h    = (const float*)d_in[0];
    const int*   ei   = (const int*)d_in[1];
    const float* ew   = (const float*)d_in[2];
    const float* g1   = (const float*)d_in[3];
    const float* be1  = (const float*)d_in[4];
    const float* rm1  = (const float*)d_in[5];
    const float* rv1  = (const float*)d_in[6];
    const float* Wl   = (const float*)d_in[7];
    const float* bl   = (const float*)d_in[8];
    const float* Wr   = (const float*)d_in[9];
    const float* br   = (const float*)d_in[10];
    const float* We   = (const float*)d_in[11];
    const float* att  = (const float*)d_in[12];
    const float* bias_gat = (const float*)d_in[13];
    const float* W1   = (const float*)d_in[14];
    const float* b1   = (const float*)d_in[15];
    const float* g2   = (const float*)d_in[16];
    const float* be2  = (const float*)d_in[17];
    const float* rm2  = (const float*)d_in[18];
    const float* rv2  = (const float*)d_in[19];
    const float* W2   = (const float*)d_in[20];
    const float* b2   = (const float*)d_in[21];

    float* ws  = (float*)d_ws;
    float* hbn = ws + OFF_HBN;
    float* acc = ws + OFF_ACC;

    hipMemsetAsync(acc, 0, (size_t)N_NODES * 16 * 4, stream);
    k_bn1<<<(N_NODES * 8 + 255) / 256, 256, 0, stream>>>(h, g1, be1, rm1, rv1, hbn);
    k_edge<<<2048, 256, 0, stream>>>(hbn, ei, ew, Wl, bl, Wr, br, We, att, acc);
    k_mlp<<<512, 256, 0, stream>>>(acc, Wl, bl, bias_gat, W1, b1, g2, be2, rm2, rv2, W2, b2,
                                   (float*)d_out);
}